// Round 17
// baseline (398.970 us; speedup 1.0000x reference)
//
#include <hip/hip_runtime.h>
#include <math.h>

#define HIDDEN 64
#define N_LAYERS 4
#define N_CLASSES 10
#define N_GRAPHS 512
#define BSH 8                        // coarse bucket: 256 nodes
#define NPB 256                      // nodes per bucket
#define PART_K 2048                  // edges per partition block

typedef _Float16 __h;
typedef __attribute__((ext_vector_type(4))) _Float16 half4;   // 8 B
typedef __attribute__((ext_vector_type(8))) _Float16 half8;   // 16 B, MFMA A/B frag
typedef __attribute__((ext_vector_type(4))) float f32x4;      // MFMA acc

// ---------------- pass 1: global bucket histogram ----------------
__global__ __launch_bounds__(256) void k_histA(const int* __restrict__ dst,
                                               int* __restrict__ ghist, int E, int NB) {
    __shared__ int hist[512];
    int t = threadIdx.x;
    hist[t] = 0; hist[t + 256] = 0;
    __syncthreads();
    int base = blockIdx.x * PART_K;
    int kend = min(PART_K, E - base);
    for (int k = t; k < kend; k += 256) atomicAdd(&hist[dst[base + k] >> BSH], 1);
    __syncthreads();
    for (int j = t; j < NB; j += 256) {
        int h = hist[j];
        if (h) atomicAdd(&ghist[j], h);
    }
}

// ---------------- pass 2: scan bucket sizes -> bases, init cursors ----------------
__global__ __launch_bounds__(256) void k_bucketscan(const int* __restrict__ ghist,
                                                    int* __restrict__ bucketbase,
                                                    int* __restrict__ gcur, int NB) {
    __shared__ int s[256];
    int t = threadIdx.x;
    int j0 = 2 * t, j1 = 2 * t + 1;
    int h0 = (j0 < NB) ? ghist[j0] : 0;
    int h1 = (j1 < NB) ? ghist[j1] : 0;
    s[t] = h0 + h1; __syncthreads();
    for (int o = 1; o < 256; o <<= 1) {
        int x = (t >= o) ? s[t - o] : 0;
        __syncthreads();
        s[t] += x;
        __syncthreads();
    }
    int base = (t == 0) ? 0 : s[t - 1];
    if (j0 <= NB) { bucketbase[j0] = base;      gcur[j0] = base; }
    if (j1 <= NB) { bucketbase[j1] = base + h0; gcur[j1] = base + h0; }
}

// ---------------- pass 3: partition edges into bucket segments (LDS reorder) ----------------
__global__ __launch_bounds__(256) void k_partition(const int* __restrict__ src,
                                                   const int* __restrict__ dst,
                                                   int* __restrict__ gcur,
                                                   int* __restrict__ packed,
                                                   int E, int NB) {
    __shared__ int hist[512];
    __shared__ int scanE[512];
    __shared__ int cur[512];
    __shared__ int delta[512];
    __shared__ int ps[256];
    __shared__ int stage[PART_K];
    int t = threadIdx.x;
    int base = blockIdx.x * PART_K;
    int kend = min(PART_K, E - base);

    hist[t] = 0; hist[t + 256] = 0;
    __syncthreads();
    for (int k = t; k < kend; k += 256) atomicAdd(&hist[dst[base + k] >> BSH], 1);
    __syncthreads();

    int j0 = 2 * t, j1 = j0 + 1;
    int h0 = hist[j0], h1 = hist[j1];
    ps[t] = h0 + h1; __syncthreads();
    for (int o = 1; o < 256; o <<= 1) {
        int x = (t >= o) ? ps[t - o] : 0;
        __syncthreads();
        ps[t] += x;
        __syncthreads();
    }
    int bexc = (t == 0) ? 0 : ps[t - 1];
    scanE[j0] = bexc;
    scanE[j1] = bexc + h0;
    __syncthreads();

    for (int j = t; j < NB; j += 256) {
        int h = hist[j];
        int g = h ? atomicAdd(&gcur[j], h) : 0;
        delta[j] = g - scanE[j];
        cur[j]   = scanE[j];
    }
    __syncthreads();

    for (int k = t; k < kend; k += 256) {
        int d = dst[base + k], s = src[base + k];
        int j = d >> BSH;
        int pos = atomicAdd(&cur[j], 1);
        stage[pos] = (s << BSH) | (d & (NPB - 1));
    }
    __syncthreads();

    for (int i = t; i < kend; i += 256) {
        int lo = 0, hi = NB;
        while (hi - lo > 1) {
            int mid = (lo + hi) >> 1;
            if (scanE[mid] <= i) lo = mid; else hi = mid;
        }
        packed[i + delta[lo]] = stage[i];
    }
}

// ---------------- pass 4: per-bucket CSR fill with SELF-EDGE prepend ----------------
// csr gets E+N entries: each node's segment = [self, edges...].
__global__ __launch_bounds__(256) void k_fill3(const int* __restrict__ packed,
                                               const int* __restrict__ bucketbase,
                                               int* __restrict__ rowptr,
                                               float* __restrict__ dis,
                                               int* __restrict__ csr_src,
                                               int N, int E) {
    __shared__ int cnt[256];
    __shared__ int rp[256];
    int j = blockIdx.x;
    int t = threadIdx.x;
    int node0 = j << BSH;
    int segb = bucketbase[j];
    int sege = bucketbase[j + 1];

    cnt[t] = 0; __syncthreads();
    for (int i = segb + t; i < sege; i += 256) atomicAdd(&cnt[packed[i] & (NPB - 1)], 1);
    __syncthreads();

    int c = cnt[t];
    rp[t] = c; __syncthreads();
    for (int o = 1; o < 256; o <<= 1) {
        int x = (t >= o) ? rp[t - o] : 0;
        __syncthreads();
        rp[t] += x;
        __syncthreads();
    }
    int node = node0 + t;
    int start = segb + rp[t] - c + node;   // + node = selves before this node
    if (node < N) {
        rowptr[node] = start;
        dis[node] = rsqrtf((float)c + 1.0f);
        csr_src[start] = node;             // self edge first
        if (node == N - 1) rowptr[N] = E + N;
    }
    __syncthreads();
    cnt[t] = start + 1;
    __syncthreads();
    for (int i = segb + t; i < sege; i += 256) {
        int v = packed[i];
        int slot = atomicAdd(&cnt[v & (NPB - 1)], 1);
        csr_src[slot] = v >> BSH;
    }
}

// ---------------- prep: W_conv (l=0..3) + W_enc (l=4) -> fp16 B-fragment layout ----------------
__global__ __launch_bounds__(256) void k_prepW(const float* __restrict__ Wconv,
                                               const float* __restrict__ Wenc,
                                               __h* __restrict__ Wh) {
    int idx = blockIdx.x * 256 + threadIdx.x;        // l*4096 + k*64 + n
    int l = idx >> 12;
    int kn = idx & 4095;
    int k = kn >> 6, n = kn & 63;
    int nt = n >> 4, nl = n & 15;
    int kt = k >> 5, kr = k & 31;
    int quad = kr >> 3, jj = kr & 7;
    int lane = quad * 16 + nl;
    int pos = (((nt * 2 + kt) * 64 + lane) << 3) + jj;
    float w = (l < N_LAYERS) ? Wconv[(size_t)l * 4096 + kn] : Wenc[kn];
    Wh[(l << 12) + pos] = (__h)w;
}

// ---------------- encoder GEMM: fp32 x @ fp16 W, 32 rows/wave ----------------
__global__ __launch_bounds__(256) void k_enc(const float* __restrict__ xf,
                                             const __h* __restrict__ Wh,
                                             const float* __restrict__ bias,
                                             const float* __restrict__ dis,
                                             __h* __restrict__ Gho, int N) {
    int wave = threadIdx.x >> 6;
    int lane = threadIdx.x & 63;
    int row0 = (blockIdx.x * 4 + wave) * 32;
    if (row0 >= N) return;
    int quad = lane >> 4, nl = lane & 15;

    half8 bf[4][2];
    #pragma unroll
    for (int nt = 0; nt < 4; ++nt)
        #pragma unroll
        for (int kt = 0; kt < 2; ++kt)
            bf[nt][kt] = *(const half8*)(Wh + (((nt * 2 + kt) * 64 + lane) << 3));

    f32x4 acc[2][4];
    #pragma unroll
    for (int h = 0; h < 2; ++h) {
        int r = row0 + h * 16 + nl; if (r >= N) r = N - 1;
        const float* ap = xf + (size_t)r * 64 + quad * 8;
        float4 v0 = ((const float4*)ap)[0];
        float4 v1 = ((const float4*)ap)[1];
        float4 v2 = ((const float4*)(ap + 32))[0];
        float4 v3 = ((const float4*)(ap + 32))[1];
        half8 a0 = (half8){(__h)v0.x, (__h)v0.y, (__h)v0.z, (__h)v0.w,
                           (__h)v1.x, (__h)v1.y, (__h)v1.z, (__h)v1.w};
        half8 a1 = (half8){(__h)v2.x, (__h)v2.y, (__h)v2.z, (__h)v2.w,
                           (__h)v3.x, (__h)v3.y, (__h)v3.z, (__h)v3.w};
        #pragma unroll
        for (int nt = 0; nt < 4; ++nt) {
            acc[h][nt] = (f32x4){0.f, 0.f, 0.f, 0.f};
            acc[h][nt] = __builtin_amdgcn_mfma_f32_16x16x32_f16(a0, bf[nt][0], acc[h][nt], 0, 0, 0);
            acc[h][nt] = __builtin_amdgcn_mfma_f32_16x16x32_f16(a1, bf[nt][1], acc[h][nt], 0, 0, 0);
        }
    }

    float b[4];
    #pragma unroll
    for (int nt = 0; nt < 4; ++nt) b[nt] = bias[nt * 16 + nl];
    #pragma unroll
    for (int h = 0; h < 2; ++h)
        #pragma unroll
        for (int reg = 0; reg < 4; ++reg) {
            int rr = row0 + h * 16 + quad * 4 + reg;
            if (rr < N) {
                float ds = dis[rr];
                #pragma unroll
                for (int nt = 0; nt < 4; ++nt)
                    Gho[(size_t)rr * 64 + nt * 16 + nl] = (__h)(ds * (acc[h][nt][reg] + b[nt]));
            }
        }
}

// ---------------- fused layer: register-level gather -> MFMA -> epilogue ----------------
// Lane (quad,nl) accumulates its own A-fragment over node nl's CSR segment
// (self-edge included). Masked slots read the always-zero row N.
// mode 1 (mid): Gout = fp16( dis * silu(v + b) );  mode 2 (last): pooled += silu(v + b)
__global__ __launch_bounds__(256) void k_layer(const int* __restrict__ csr_src,
                                               const int* __restrict__ rowptr,
                                               const float* __restrict__ dis,
                                               const __h* __restrict__ G,
                                               const __h* __restrict__ Wh,
                                               const float* __restrict__ bias,
                                               const int* __restrict__ batch,
                                               __h* __restrict__ Gout,
                                               float* __restrict__ pooled,
                                               int N, int last) {
    int wave = threadIdx.x >> 6;
    int lane = threadIdx.x & 63;
    int row0 = (blockIdx.x * 4 + wave) * 32;
    if (row0 >= N) return;
    int quad = lane >> 4, nl = lane & 15;

    half8 bf[4][2];
    #pragma unroll
    for (int nt = 0; nt < 4; ++nt)
        #pragma unroll
        for (int kt = 0; kt < 2; ++kt)
            bf[nt][kt] = *(const half8*)(Wh + (((nt * 2 + kt) * 64 + lane) << 3));

    f32x4 acc[2][4];
    #pragma unroll
    for (int h = 0; h < 2; ++h) {
        int node = row0 + h * 16 + nl;
        if (node >= N) node = N - 1;
        int beg = rowptr[node];
        int len = rowptr[node + 1] - beg;
        // wave-max segment length (lanes xor 1,2,4,8 span the 16 nodes in each quad group)
        int ml = len;
        #pragma unroll
        for (int m = 1; m < 16; m <<= 1) {
            int o = __shfl_xor(ml, m);
            ml = (o > ml) ? o : ml;
        }

        half8 sa = {(__h)0.f, (__h)0.f, (__h)0.f, (__h)0.f,
                    (__h)0.f, (__h)0.f, (__h)0.f, (__h)0.f};
        half8 sb = sa;
        for (int j = 0; j < ml; j += 4) {
            #pragma unroll
            for (int u = 0; u < 4; ++u) {
                int jj = j + u;
                int cidx = beg + ((jj < len) ? jj : (len - 1));
                int s = csr_src[cidx];
                if (jj >= len) s = N;                 // zero row
                const __h* gp = G + (size_t)s * 64 + quad * 8;
                half8 r0 = *(const half8*)gp;
                half8 r1 = *(const half8*)(gp + 32);
                sa += r0;
                sb += r1;
            }
        }
        __h dd = (__h)dis[node];
        half8 a0 = sa * dd;
        half8 a1 = sb * dd;
        #pragma unroll
        for (int nt = 0; nt < 4; ++nt) {
            acc[h][nt] = (f32x4){0.f, 0.f, 0.f, 0.f};
            acc[h][nt] = __builtin_amdgcn_mfma_f32_16x16x32_f16(a0, bf[nt][0], acc[h][nt], 0, 0, 0);
            acc[h][nt] = __builtin_amdgcn_mfma_f32_16x16x32_f16(a1, bf[nt][1], acc[h][nt], 0, 0, 0);
        }
    }

    float b[4];
    #pragma unroll
    for (int nt = 0; nt < 4; ++nt) b[nt] = bias[nt * 16 + nl];

    if (!last) {
        #pragma unroll
        for (int h = 0; h < 2; ++h)
            #pragma unroll
            for (int reg = 0; reg < 4; ++reg) {
                int rr = row0 + h * 16 + quad * 4 + reg;
                if (rr < N) {
                    float ds = dis[rr];
                    #pragma unroll
                    for (int nt = 0; nt < 4; ++nt) {
                        float v = acc[h][nt][reg] + b[nt];
                        v = v / (1.0f + expf(-v));
                        Gout[(size_t)rr * 64 + nt * 16 + nl] = (__h)(ds * v);
                    }
                }
            }
    } else {
        float run[4] = {0.f, 0.f, 0.f, 0.f};
        int cur = -1;
        #pragma unroll
        for (int h = 0; h < 2; ++h)
            #pragma unroll
            for (int reg = 0; reg < 4; ++reg) {
                int rr = row0 + h * 16 + quad * 4 + reg;
                if (rr < N) {
                    int bi = batch[rr];
                    float vals[4];
                    #pragma unroll
                    for (int nt = 0; nt < 4; ++nt) {
                        float v = acc[h][nt][reg] + b[nt];
                        vals[nt] = v / (1.0f + expf(-v));
                    }
                    if (bi != cur) {
                        if (cur >= 0) {
                            #pragma unroll
                            for (int nt = 0; nt < 4; ++nt)
                                atomicAdd(&pooled[cur * 64 + nt * 16 + nl], run[nt]);
                        }
                        cur = bi;
                        #pragma unroll
                        for (int nt = 0; nt < 4; ++nt) run[nt] = vals[nt];
                    } else {
                        #pragma unroll
                        for (int nt = 0; nt < 4; ++nt) run[nt] += vals[nt];
                    }
                }
            }
        if (cur >= 0) {
            #pragma unroll
            for (int nt = 0; nt < 4; ++nt)
                atomicAdd(&pooled[cur * 64 + nt * 16 + nl], run[nt]);
        }
    }
}

// ---------------- readout ----------------
__global__ __launch_bounds__(256) void k_readout(const float* __restrict__ pooled,
                                                 const float* __restrict__ Wout,
                                                 const float* __restrict__ bout,
                                                 float* __restrict__ out) {
    int idx = blockIdx.x * 256 + threadIdx.x;
    if (idx >= N_GRAPHS * N_CLASSES) return;
    int g = idx / N_CLASSES, c = idx % N_CLASSES;
    float s = bout[c];
    #pragma unroll
    for (int j = 0; j < 64; ++j) s += pooled[g * 64 + j] * Wout[j * N_CLASSES + c];
    out[idx] = fmaxf(s, 0.0f);
}

extern "C" void kernel_launch(void* const* d_in, const int* in_sizes, int n_in,
                              void* d_out, int out_size, void* d_ws, size_t ws_size,
                              hipStream_t stream) {
    const float* x      = (const float*)d_in[0];
    const int*   ei     = (const int*)d_in[1];
    const int*   batch  = (const int*)d_in[2];
    const float* W_enc  = (const float*)d_in[3];
    const float* b_enc  = (const float*)d_in[4];
    const float* W_conv = (const float*)d_in[5];
    const float* b_conv = (const float*)d_in[6];
    const float* W_out  = (const float*)d_in[7];
    const float* b_out  = (const float*)d_in[8];
    float* out = (float*)d_out;

    const int N = in_sizes[2];
    const int E = in_sizes[1] / 2;
    const int* src = ei;
    const int* dst = ei + E;
    const int NB   = (N + NPB - 1) >> BSH;
    const int NBLK = (E + PART_K - 1) / PART_K;

    char* ws = (char*)d_ws;
    size_t off = 0;
    auto alloc = [&](size_t bytes) -> char* {
        char* p = ws + off;
        off += (bytes + 255) & ~(size_t)255;
        return p;
    };
    int*   ghist      = (int*)alloc((size_t)(NB + 1) * sizeof(int));
    int*   bucketbase = (int*)alloc((size_t)(NB + 1) * sizeof(int));
    int*   gcur       = (int*)alloc((size_t)(NB + 1) * sizeof(int));
    int*   packed     = (int*)alloc((size_t)E * sizeof(int));
    int*   csr_src    = (int*)alloc((size_t)(E + N) * sizeof(int));
    int*   rowptr     = (int*)alloc((size_t)(N + 1) * sizeof(int));
    float* dis        = (float*)alloc((size_t)N * sizeof(float));
    __h*   GhA        = (__h*)alloc((size_t)(N + 1) * HIDDEN * sizeof(__h));  // +1: zero row
    __h*   GhB        = (__h*)alloc((size_t)(N + 1) * HIDDEN * sizeof(__h));
    __h*   Wh         = (__h*)alloc((size_t)(N_LAYERS + 1) * 4096 * sizeof(__h));
    float* pooled     = (float*)alloc((size_t)N_GRAPHS * HIDDEN * sizeof(float));
    (void)ws_size;

    hipMemsetAsync(ghist, 0, (size_t)(NB + 1) * sizeof(int), stream);
    hipMemsetAsync(pooled, 0, (size_t)N_GRAPHS * HIDDEN * sizeof(float), stream);
    hipMemsetAsync(GhA + (size_t)N * HIDDEN, 0, HIDDEN * sizeof(__h), stream);  // zero row
    hipMemsetAsync(GhB + (size_t)N * HIDDEN, 0, HIDDEN * sizeof(__h), stream);

    k_histA     <<<NBLK, 256, 0, stream>>>(dst, ghist, E, NB);
    k_bucketscan<<<1,    256, 0, stream>>>(ghist, bucketbase, gcur, NB);
    k_partition <<<NBLK, 256, 0, stream>>>(src, dst, gcur, packed, E, NB);
    k_fill3     <<<NB,   256, 0, stream>>>(packed, bucketbase, rowptr, dis, csr_src, N, E);
    k_prepW<<<((N_LAYERS + 1) * 4096) / 256, 256, 0, stream>>>(W_conv, W_enc, Wh);

    int gb32 = (N + 127) / 128;   // 32 rows/wave, 4 waves/block
    // encoder: GhA = fp16(dis * (x @ W_enc + b_enc))
    k_enc<<<gb32, 256, 0, stream>>>(x, Wh + (size_t)N_LAYERS * 4096, b_enc, dis, GhA, N);

    __h* gin = GhA;
    __h* gout = GhB;
    for (int l = 0; l < N_LAYERS; ++l) {
        int last = (l == N_LAYERS - 1);
        k_layer<<<gb32, 256, 0, stream>>>(csr_src, rowptr, dis, gin,
                                          Wh + (size_t)l * 4096,
                                          b_conv + (size_t)l * HIDDEN, batch,
                                          gout, pooled, N, last);
        __h* t = gin; gin = gout; gout = t;
    }

    k_readout<<<(N_GRAPHS * N_CLASSES + 255) / 256, 256, 0, stream>>>(pooled, W_out, b_out, out);
}